// Round 4
// baseline (213.142 us; speedup 1.0000x reference)
//
#include <hip/hip_runtime.h>
#include <hip/hip_bf16.h>

typedef __bf16 bf16;
typedef __bf16 v8bf __attribute__((ext_vector_type(8)));
typedef __bf16 v4bf __attribute__((ext_vector_type(4)));
typedef float v4f __attribute__((ext_vector_type(4)));

#define HW 4096
#define CH 256
#define KC 32
#define RD 16
#define NB 2
#define BNEPS 1e-5f
#define VSTRIDE 4224   // HW + 128: breaks 8KB power-of-2 L2 channel camping on V^T reads

// ---------------- workspace byte offsets (total ~28.3 MiB) ----------------
#define OFF_MEAN   0u          // f32 [2][256]
#define OFF_WKB    4096u       // f32 [2][32][256] gate-folded Wk
#define OFF_QT     69632u      // bf16 [2][4096][32]
#define OFF_KT     593920u     // bf16 [2][4096][32]
#define OFF_BS1    1118208u    // bf16 [2][4096][32] pooled b1
#define OFF_BS2    1642496u    // bf16 [2][4096][32] pooled b2
#define OFF_VT     2166784u    // bf16 [2][256][VSTRIDE] V transposed (padded rows)
#define OFF_B1R    6492160u    // f32 [2][4096][32] raw relu(Wb1 x)
#define OFF_B2R    7540736u    // f32 [2][4096][32]
#define OFF_CTX    8589312u    // bf16 [2][4096][256]
#define OFF_PACC   12783616u   // bf16 [2048][16][256] split-K partial ctx
#define OFF_PL     29560832u   // f32 [2048*16] partial softmax denominators

// ---------------- K1: per-(b,c) spatial mean ----------------
__global__ __launch_bounds__(256) void k_mean(const float* __restrict__ x,
                                              float* __restrict__ mean) {
  int bc = blockIdx.x;                       // 0..511
  const float* px = x + (size_t)bc * HW;
  float s = 0.f;
  for (int i = threadIdx.x; i < HW; i += 256) s += px[i];
  __shared__ float red[256];
  red[threadIdx.x] = s; __syncthreads();
  for (int st = 128; st > 0; st >>= 1) {
    if (threadIdx.x < st) red[threadIdx.x] += red[threadIdx.x + st];
    __syncthreads();
  }
  if (threadIdx.x == 0) mean[bc] = red[0] * (1.0f / HW);
}

// ---------------- K2: GatherExcite MLP gate, folded into Wk ----------------
__global__ __launch_bounds__(256) void k_gate(const float* __restrict__ mean,
    const float* __restrict__ gw1, const float* __restrict__ gb1,
    const float* __restrict__ gw2, const float* __restrict__ gb2,
    const float* __restrict__ Wk, float* __restrict__ wkb) {
  int b = blockIdx.x;
  int t = threadIdx.x;                        // = channel c
  __shared__ float ms[CH];
  __shared__ float hid[RD];
  ms[t] = mean[b * CH + t];
  __syncthreads();
  if (t < RD) {
    float a = gb1[t];
    for (int c = 0; c < CH; ++c) a += gw1[t * CH + c] * ms[c];
    hid[t] = fmaxf(a, 0.f);
  }
  __syncthreads();
  float a = gb2[t];
  #pragma unroll
  for (int r = 0; r < RD; ++r) a += gw2[t * RD + r] * hid[r];
  float s = 1.f / (1.f + __expf(-a));         // sigmoid gate for channel t
  for (int kk = 0; kk < KC; ++kk)
    wkb[((size_t)b * KC + kk) * CH + t] = Wk[kk * CH + t] * s;
}

// ---------------- K3: fused 1x1 projections  ----------------
__global__ __launch_bounds__(256, 2) void k_proj(
    const float* __restrict__ x, const float* __restrict__ Wq,
    const float* __restrict__ wkb, const float* __restrict__ Wb1,
    const float* __restrict__ Wb2, const float* __restrict__ Wv,
    bf16* __restrict__ qt, bf16* __restrict__ kt,
    float* __restrict__ b1r, float* __restrict__ b2r, bf16* __restrict__ vt) {
  __shared__ __align__(16) float xs[CH * 36];
  const int blk  = blockIdx.x;
  const int half = blk & 1;
  const int nn   = (blk >> 1) & 127;
  const int b    = blk >> 8;
  const int n0   = nn * 32;
  const int t    = threadIdx.x;
  {
    const int j = t & 31, crow = t >> 5;
    const float* xb = x + ((size_t)b * CH) * HW + n0;
    #pragma unroll
    for (int i = 0; i < 32; ++i) {
      int c = crow + 8 * i;
      xs[c * 36 + j] = xb[(size_t)c * HW + j];
    }
  }
  __syncthreads();
  const int og = t >> 3;
  const int jg = t & 7;
  const float* wkb_b = wkb + (size_t)b * KC * CH;
  const float* wp[6];
  #pragma unroll
  for (int oo = 0; oo < 6; ++oo) {
    int o = half * 192 + og * 6 + oo;
    const float* w;
    if (o < 32)       w = Wq   + o * CH;
    else if (o < 64)  w = wkb_b + (o - 32) * CH;
    else if (o < 96)  w = Wb1  + (o - 64) * CH;
    else if (o < 128) w = Wb2  + (o - 96) * CH;
    else              w = Wv   + (o - 128) * CH;
    wp[oo] = w;
  }
  float acc[6][4];
  #pragma unroll
  for (int oo = 0; oo < 6; ++oo)
    #pragma unroll
    for (int jj = 0; jj < 4; ++jj) acc[oo][jj] = 0.f;
  for (int c0 = 0; c0 < CH; c0 += 4) {
    v4f xv[4];
    #pragma unroll
    for (int cc = 0; cc < 4; ++cc)
      xv[cc] = *(const v4f*)&xs[(c0 + cc) * 36 + jg * 4];
    #pragma unroll
    for (int oo = 0; oo < 6; ++oo) {
      v4f wv = *(const v4f*)(wp[oo] + c0);
      #pragma unroll
      for (int cc = 0; cc < 4; ++cc)
        #pragma unroll
        for (int jj = 0; jj < 4; ++jj)
          acc[oo][jj] += wv[cc] * xv[cc][jj];
    }
  }
  #pragma unroll
  for (int oo = 0; oo < 6; ++oo) {
    int o = half * 192 + og * 6 + oo;
    #pragma unroll
    for (int jj = 0; jj < 4; ++jj) {
      int n = n0 + jg * 4 + jj;
      size_t nb = (size_t)b * HW + n;
      float v = acc[oo][jj];
      if (o < 32)       qt[nb * KC + o] = (bf16)v;
      else if (o < 64)  kt[nb * KC + (o - 32)] = (bf16)v;
      else if (o < 96)  b1r[nb * KC + (o - 64)] = fmaxf(v, 0.f);
      else if (o < 128) b2r[nb * KC + (o - 96)] = fmaxf(v, 0.f);
      else              vt[((size_t)b * CH + (o - 128)) * VSTRIDE + n] = (bf16)v;
    }
  }
}

// ---------------- K3b: 1-D 3-tap pool of the bias factors ----------------
__global__ __launch_bounds__(256) void k_pool(const float* __restrict__ b1r,
    const float* __restrict__ b2r, bf16* __restrict__ bs1, bf16* __restrict__ bs2) {
  int i = blockIdx.x * 256 + threadIdx.x;
  int n = (i >> 5) & (HW - 1);
  float a = b1r[i], c = b2r[i];
  if (n > 0)      { a += b1r[i - KC]; c += b2r[i - KC]; }
  if (n < HW - 1) { a += b1r[i + KC]; c += b2r[i + KC]; }
  bs1[i] = (bf16)a;
  bs2[i] = (bf16)c;
}

// ---------------- K4: flash attention, no-max softmax, 4 waves/block ----------------
// blk = ((b*256+rg)*4+os); wave w handles keys [os*1024 + w*256, +256), 16 query rows
__global__ __launch_bounds__(256, 2) void k_attn(
    const bf16* __restrict__ qtg, const bf16* __restrict__ ktg,
    const bf16* __restrict__ bs1g, const bf16* __restrict__ bs2g,
    const bf16* __restrict__ vtg, const float* __restrict__ wgb,
    bf16* __restrict__ pacc, float* __restrict__ pl) {
  // LDS arena: [racc f32[4][16][68] = 17408 B][ps f32[4][16][16] = 4096 B]
  // plds (bf16[4][16*72] = 9216 B) aliases the racc region during the main loop.
  __shared__ __align__(16) char arena[17408 + 4096];
  float (*racc)[16][68] = (float (*)[16][68])arena;
  float (*ps)[16][16]   = (float (*)[16][16])(arena + 17408);
  const int blk = blockIdx.x;
  const int b   = blk >> 10;
  const int rg  = (blk >> 2) & 255;
  const int os  = blk & 3;
  const int w   = threadIdx.x >> 6;
  const int lane = threadIdx.x & 63;
  const int cl = lane & 15;
  const int kh = lane >> 4;
  const int kb = os * 1024 + w * 256;
  bf16* pw = (bf16*)arena + w * (16 * 72);     // per-wave P relayout buffer
  const float wscale = wgb[0] * (1.f / 9.f);
  const v4f vzero = {0.f, 0.f, 0.f, 0.f};
  const size_t qoff = ((size_t)(b * HW + rg * 16 + cl)) * KC + kh * 8;
  const v8bf qf  = *(const v8bf*)(qtg + qoff);
  const v8bf b1f = *(const v8bf*)(bs1g + qoff);
  const bf16* kt = ktg + (size_t)b * HW * KC;
  const bf16* b2 = bs2g + (size_t)b * HW * KC;
  const bf16* vt = vtg + (size_t)b * CH * VSTRIDE;
  v4f acc[16];
  #pragma unroll
  for (int f = 0; f < 16; ++f) acc[f] = vzero;
  float psum[4] = {0.f, 0.f, 0.f, 0.f};

  for (int tt = 0; tt < 4; ++tt) {
    const int m0 = kb + tt * 64;
    v4f sim[4], bia[4];
    #pragma unroll
    for (int cb = 0; cb < 4; ++cb) {
      size_t ko = ((size_t)(m0 + cb * 16 + cl)) * KC + kh * 8;
      v8bf kf  = *(const v8bf*)(kt + ko);
      v8bf b2f = *(const v8bf*)(b2 + ko);
      sim[cb] = __builtin_amdgcn_mfma_f32_16x16x32_bf16(qf,  kf,  vzero, 0, 0, 0);
      bia[cb] = __builtin_amdgcn_mfma_f32_16x16x32_bf16(b1f, b2f, vzero, 0, 0, 0);
    }
    // scores bounded (|sim| ~< 25): exp without max subtraction, no cross-lane ops
    float p[4][4];
    #pragma unroll
    for (int cb = 0; cb < 4; ++cb)
      #pragma unroll
      for (int r = 0; r < 4; ++r) {
        float z = wscale * bia[cb][r];
        float bm = 1.f / (1.f + __expf(-z));
        float pv = __expf(sim[cb][r] * bm);
        p[cb][r] = pv;
        psum[r] += pv;
      }
    // relayout P (C-layout) -> A-fragment via per-wave LDS (single buffer;
    // per-wave DS ops are in-order, lgkmcnt(0) orders write->read)
    #pragma unroll
    for (int cb = 0; cb < 4; ++cb)
      #pragma unroll
      for (int r = 0; r < 4; ++r)
        pw[(kh * 4 + r) * 72 + cb * 16 + cl] = (bf16)p[cb][r];
    asm volatile("s_waitcnt lgkmcnt(0)" ::: "memory");
    const v8bf pa0 = *(const v8bf*)&pw[cl * 72 + kh * 8];
    const v8bf pa1 = *(const v8bf*)&pw[cl * 72 + 32 + kh * 8];
    #pragma unroll
    for (int f = 0; f < 16; ++f) {
      size_t vo = ((size_t)(f * 16 + cl)) * VSTRIDE + (m0 + kh * 8);
      v8bf v0 = *(const v8bf*)(vt + vo);
      v8bf v1 = *(const v8bf*)(vt + vo + 32);
      acc[f] = __builtin_amdgcn_mfma_f32_16x16x32_bf16(pa0, v0, acc[f], 0, 0, 0);
      acc[f] = __builtin_amdgcn_mfma_f32_16x16x32_bf16(pa1, v1, acc[f], 0, 0, 0);
    }
  }
  // ---- block reduce (plain sums; no max bookkeeping) ----
  #pragma unroll
  for (int r = 0; r < 4; ++r) ps[w][kh * 4 + r][cl] = psum[r];
  bf16* po = pacc + (size_t)blk * 16 * CH;
  const int t = threadIdx.x;
  for (int c4 = 0; c4 < 4; ++c4) {
    __syncthreads();                           // also drains last plds reads before racc overlap
    #pragma unroll
    for (int ff = 0; ff < 4; ++ff) {
      int f = c4 * 4 + ff;
      #pragma unroll
      for (int r = 0; r < 4; ++r)
        racc[w][kh * 4 + r][ff * 16 + cl] = acc[f][r];
    }
    __syncthreads();
    if (c4 == 0 && t < 16) {
      float s = 0.f;
      #pragma unroll
      for (int w4 = 0; w4 < 4; ++w4)
        for (int c = 0; c < 16; ++c) s += ps[w4][t][c];
      pl[blk * 16 + t] = s;
    }
    int row = t >> 4, cc = (t & 15) * 4;
    v4f s = *(const v4f*)&racc[0][row][cc];
    #pragma unroll
    for (int w4 = 1; w4 < 4; ++w4) s += *(const v4f*)&racc[w4][row][cc];
    v4bf sb;
    #pragma unroll
    for (int j = 0; j < 4; ++j) sb[j] = (bf16)s[j];
    *(v4bf*)&po[row * CH + c4 * 64 + cc] = sb;
  }
}

// ---------------- K4b: split-K combine (plain sum + divide) ----------------
__global__ __launch_bounds__(256) void k_combine(const bf16* __restrict__ pacc,
    const float* __restrict__ pl, bf16* __restrict__ ctx) {
  const int r = blockIdx.x * 4 + (threadIdx.x >> 6);   // global row 0..8191
  const int lane = threadIdx.x & 63;
  const int b = r >> 12;
  const int n = r & (HW - 1);
  const int rg = n >> 4, rl = n & 15;
  const int base = (b * 256 + rg) * 4;
  float den = 0.f;
  #pragma unroll
  for (int s = 0; s < 4; ++s) den += pl[(base + s) * 16 + rl];
  const float inv = 1.f / den;
  #pragma unroll
  for (int c0 = 0; c0 < CH; c0 += 64) {
    int c = c0 + lane;
    float a = 0.f;
    #pragma unroll
    for (int s = 0; s < 4; ++s)
      a += (float)pacc[((size_t)(base + s) * 16 + rl) * CH + c];
    ctx[(size_t)r * CH + c] = (bf16)(a * inv);
  }
}

// ---------------- K5: output 1x1 conv + BN + ReLU + residual ----------------
__global__ __launch_bounds__(256, 2) void k_out(
    const bf16* __restrict__ ctx, const float* __restrict__ Wo,
    const float* __restrict__ bns, const float* __restrict__ bnb,
    const float* __restrict__ bnm, const float* __restrict__ bnv,
    const float* __restrict__ gamma, const float* __restrict__ x,
    float* __restrict__ out) {
  __shared__ __align__(16) float cs[CH * 36];
  const int blk  = blockIdx.x;
  const int half = blk & 1;
  const int nn   = (blk >> 1) & 127;
  const int b    = blk >> 8;
  const int n0   = nn * 32;
  const int t    = threadIdx.x;
  for (int i = t; i < 32 * 256; i += 256) {
    int j = i >> 8, c = i & 255;
    cs[c * 36 + j] = (float)ctx[((size_t)b * HW + n0 + j) * CH + c];
  }
  __syncthreads();
  const int og = t >> 3, jg = t & 7;
  float acc[4][4];
  #pragma unroll
  for (int oo = 0; oo < 4; ++oo)
    #pragma unroll
    for (int jj = 0; jj < 4; ++jj) acc[oo][jj] = 0.f;
  const int o0 = half * 128 + og * 4;
  for (int c0 = 0; c0 < CH; c0 += 4) {
    v4f xv[4];
    #pragma unroll
    for (int cc = 0; cc < 4; ++cc)
      xv[cc] = *(const v4f*)&cs[(c0 + cc) * 36 + jg * 4];
    #pragma unroll
    for (int oo = 0; oo < 4; ++oo) {
      v4f wv = *(const v4f*)&Wo[(o0 + oo) * CH + c0];
      #pragma unroll
      for (int cc = 0; cc < 4; ++cc)
        #pragma unroll
        for (int jj = 0; jj < 4; ++jj)
          acc[oo][jj] += wv[cc] * xv[cc][jj];
    }
  }
  const float g = gamma[0];
  #pragma unroll
  for (int oo = 0; oo < 4; ++oo) {
    int o = o0 + oo;
    float isc = bns[o] / sqrtf(bnv[o] + BNEPS);
    float mu = bnm[o], bb = bnb[o];
    #pragma unroll
    for (int jj = 0; jj < 4; ++jj) {
      int n = n0 + jg * 4 + jj;
      float v = (acc[oo][jj] - mu) * isc + bb;
      v = fmaxf(v, 0.f);
      size_t oi = ((size_t)b * CH + o) * HW + n;
      out[oi] = g * v + x[oi];
    }
  }
}

// ---------------- launch ----------------
extern "C" void kernel_launch(void* const* d_in, const int* in_sizes, int n_in,
                              void* d_out, int out_size, void* d_ws, size_t ws_size,
                              hipStream_t stream) {
  const float* x    = (const float*)d_in[0];
  const float* Wq   = (const float*)d_in[1];
  const float* Wk   = (const float*)d_in[2];
  const float* Wv   = (const float*)d_in[3];
  const float* Wb1  = (const float*)d_in[4];
  const float* Wb2  = (const float*)d_in[5];
  const float* wgb  = (const float*)d_in[6];
  const float* gw1  = (const float*)d_in[7];
  const float* gb1  = (const float*)d_in[8];
  const float* gw2  = (const float*)d_in[9];
  const float* gb2  = (const float*)d_in[10];
  const float* Wo   = (const float*)d_in[11];
  const float* bns  = (const float*)d_in[12];
  const float* bnb  = (const float*)d_in[13];
  const float* bnm  = (const float*)d_in[14];
  const float* bnv  = (const float*)d_in[15];
  const float* gam  = (const float*)d_in[16];

  char* ws = (char*)d_ws;
  float* mean = (float*)(ws + OFF_MEAN);
  float* wkb  = (float*)(ws + OFF_WKB);
  bf16* qt    = (bf16*)(ws + OFF_QT);
  bf16* kt    = (bf16*)(ws + OFF_KT);
  bf16* bs1   = (bf16*)(ws + OFF_BS1);
  bf16* bs2   = (bf16*)(ws + OFF_BS2);
  bf16* vt    = (bf16*)(ws + OFF_VT);
  float* b1r  = (float*)(ws + OFF_B1R);
  float* b2r  = (float*)(ws + OFF_B2R);
  bf16* ctx   = (bf16*)(ws + OFF_CTX);
  bf16* pacc  = (bf16*)(ws + OFF_PACC);
  float* plv  = (float*)(ws + OFF_PL);
  float* out  = (float*)d_out;

  hipLaunchKernelGGL(k_mean,    dim3(NB * CH),        dim3(256), 0, stream, x, mean);
  hipLaunchKernelGGL(k_gate,    dim3(NB),             dim3(256), 0, stream, mean, gw1, gb1, gw2, gb2, Wk, wkb);
  hipLaunchKernelGGL(k_proj,    dim3(NB * 128 * 2),   dim3(256), 0, stream, x, Wq, wkb, Wb1, Wb2, Wv, qt, kt, b1r, b2r, vt);
  hipLaunchKernelGGL(k_pool,    dim3(NB * HW * KC / 256), dim3(256), 0, stream, b1r, b2r, bs1, bs2);
  hipLaunchKernelGGL(k_attn,    dim3(NB * 256 * 4),   dim3(256), 0, stream, qt, kt, bs1, bs2, vt, wgb, pacc, plv);
  hipLaunchKernelGGL(k_combine, dim3(NB * HW / 4),    dim3(256), 0, stream, pacc, plv, ctx);
  hipLaunchKernelGGL(k_out,     dim3(NB * 128 * 2),   dim3(256), 0, stream, ctx, Wo, bns, bnb, bnm, bnv, gam, x, out);
}

// Round 5
// 120.862 us; speedup vs baseline: 1.7635x; 1.7635x over previous
//
#include <hip/hip_runtime.h>
#include <hip/hip_bf16.h>

typedef __bf16 bf16;
typedef __bf16 v8bf __attribute__((ext_vector_type(8)));
typedef __bf16 v4bf __attribute__((ext_vector_type(4)));
typedef float v4f __attribute__((ext_vector_type(4)));

#define HW 4096
#define CH 256
#define KC 32
#define RD 16
#define NB 2
#define BNEPS 1e-5f
#define VSTRIDE 4224

// ---------------- workspace byte offsets ----------------
#define OFF_MEAN   0u          // f32 [2][256]
#define OFF_WKB    4096u       // f32 [2][32][256] gate-folded Wk
#define OFF_QT     69632u      // bf16 [2][4096][32]
#define OFF_KT     593920u     // bf16 [2][4096][32]
#define OFF_BS1    1118208u    // bf16 [2][4096][32] pooled b1
#define OFF_BS2    1642496u    // bf16 [2][4096][32] pooled b2
#define OFF_VT     2166784u    // bf16 [2][256][VSTRIDE] V transposed (padded rows)
#define OFF_B1R    6492160u    // f32 [2][4096][32] raw relu(Wb1 x)
#define OFF_B2R    7540736u    // f32 [2][4096][32]
#define OFF_CTX    8589312u    // bf16 [2][4096][256]
#define OFF_PACC   12783616u   // bf16 [512][64][256] split-K partial ctx
#define OFF_PL     29560832u   // f32 [512*64] partial softmax denominators

// ---------------- K1: per-(b,c) spatial mean ----------------
__global__ __launch_bounds__(256) void k_mean(const float* __restrict__ x,
                                              float* __restrict__ mean) {
  int bc = blockIdx.x;                       // 0..511
  const float* px = x + (size_t)bc * HW;
  float s = 0.f;
  for (int i = threadIdx.x; i < HW; i += 256) s += px[i];
  __shared__ float red[256];
  red[threadIdx.x] = s; __syncthreads();
  for (int st = 128; st > 0; st >>= 1) {
    if (threadIdx.x < st) red[threadIdx.x] += red[threadIdx.x + st];
    __syncthreads();
  }
  if (threadIdx.x == 0) mean[bc] = red[0] * (1.0f / HW);
}

// ---------------- K2: GatherExcite MLP gate, folded into Wk ----------------
__global__ __launch_bounds__(256) void k_gate(const float* __restrict__ mean,
    const float* __restrict__ gw1, const float* __restrict__ gb1,
    const float* __restrict__ gw2, const float* __restrict__ gb2,
    const float* __restrict__ Wk, float* __restrict__ wkb) {
  int b = blockIdx.x;
  int t = threadIdx.x;                        // = channel c
  __shared__ float ms[CH];
  __shared__ float hid[RD];
  ms[t] = mean[b * CH + t];
  __syncthreads();
  if (t < RD) {
    float a = gb1[t];
    for (int c = 0; c < CH; ++c) a += gw1[t * CH + c] * ms[c];
    hid[t] = fmaxf(a, 0.f);
  }
  __syncthreads();
  float a = gb2[t];
  #pragma unroll
  for (int r = 0; r < RD; ++r) a += gw2[t * RD + r] * hid[r];
  float s = 1.f / (1.f + __expf(-a));         // sigmoid gate for channel t
  for (int kk = 0; kk < KC; ++kk)
    wkb[((size_t)b * KC + kk) * CH + t] = Wk[kk * CH + t] * s;
}

// ---------------- K3: fused 1x1 projections  ----------------
__global__ __launch_bounds__(256, 2) void k_proj(
    const float* __restrict__ x, const float* __restrict__ Wq,
    const float* __restrict__ wkb, const float* __restrict__ Wb1,
    const float* __restrict__ Wb2, const float* __restrict__ Wv,
    bf16* __restrict__ qt, bf16* __restrict__ kt,
    float* __restrict__ b1r, float* __restrict__ b2r, bf16* __restrict__ vt) {
  __shared__ __align__(16) float xs[CH * 36];
  const int blk  = blockIdx.x;
  const int half = blk & 1;
  const int nn   = (blk >> 1) & 127;
  const int b    = blk >> 8;
  const int n0   = nn * 32;
  const int t    = threadIdx.x;
  {
    const int j = t & 31, crow = t >> 5;
    const float* xb = x + ((size_t)b * CH) * HW + n0;
    #pragma unroll
    for (int i = 0; i < 32; ++i) {
      int c = crow + 8 * i;
      xs[c * 36 + j] = xb[(size_t)c * HW + j];
    }
  }
  __syncthreads();
  const int og = t >> 3;
  const int jg = t & 7;
  const float* wkb_b = wkb + (size_t)b * KC * CH;
  const float* wp[6];
  #pragma unroll
  for (int oo = 0; oo < 6; ++oo) {
    int o = half * 192 + og * 6 + oo;
    const float* w;
    if (o < 32)       w = Wq   + o * CH;
    else if (o < 64)  w = wkb_b + (o - 32) * CH;
    else if (o < 96)  w = Wb1  + (o - 64) * CH;
    else if (o < 128) w = Wb2  + (o - 96) * CH;
    else              w = Wv   + (o - 128) * CH;
    wp[oo] = w;
  }
  float acc[6][4];
  #pragma unroll
  for (int oo = 0; oo < 6; ++oo)
    #pragma unroll
    for (int jj = 0; jj < 4; ++jj) acc[oo][jj] = 0.f;
  for (int c0 = 0; c0 < CH; c0 += 4) {
    v4f xv[4];
    #pragma unroll
    for (int cc = 0; cc < 4; ++cc)
      xv[cc] = *(const v4f*)&xs[(c0 + cc) * 36 + jg * 4];
    #pragma unroll
    for (int oo = 0; oo < 6; ++oo) {
      v4f wv = *(const v4f*)(wp[oo] + c0);
      #pragma unroll
      for (int cc = 0; cc < 4; ++cc)
        #pragma unroll
        for (int jj = 0; jj < 4; ++jj)
          acc[oo][jj] += wv[cc] * xv[cc][jj];
    }
  }
  #pragma unroll
  for (int oo = 0; oo < 6; ++oo) {
    int o = half * 192 + og * 6 + oo;
    #pragma unroll
    for (int jj = 0; jj < 4; ++jj) {
      int n = n0 + jg * 4 + jj;
      size_t nb = (size_t)b * HW + n;
      float v = acc[oo][jj];
      if (o < 32)       qt[nb * KC + o] = (bf16)v;
      else if (o < 64)  kt[nb * KC + (o - 32)] = (bf16)v;
      else if (o < 96)  b1r[nb * KC + (o - 64)] = fmaxf(v, 0.f);
      else if (o < 128) b2r[nb * KC + (o - 96)] = fmaxf(v, 0.f);
      else              vt[((size_t)b * CH + (o - 128)) * VSTRIDE + n] = (bf16)v;
    }
  }
}

// ---------------- K3b: 1-D 3-tap pool of the bias factors ----------------
__global__ __launch_bounds__(256) void k_pool(const float* __restrict__ b1r,
    const float* __restrict__ b2r, bf16* __restrict__ bs1, bf16* __restrict__ bs2) {
  int i = blockIdx.x * 256 + threadIdx.x;
  int n = (i >> 5) & (HW - 1);
  float a = b1r[i], c = b2r[i];
  if (n > 0)      { a += b1r[i - KC]; c += b2r[i - KC]; }
  if (n < HW - 1) { a += b1r[i + KC]; c += b2r[i + KC]; }
  bs1[i] = (bf16)a;
  bs2[i] = (bf16)c;
}

// ---------------- K4: flash attention, LDS-cooperative staging ----------------
// blk = rt*4 + os; rt = 64-row tile (b = rt>>6), os = key-split (1024 keys).
// 4 waves; wave w owns rows [w*16, w*16+16). 16 steps of 64 keys.
__global__ __launch_bounds__(256, 2) void k_attn(
    const bf16* __restrict__ qtg, const bf16* __restrict__ ktg,
    const bf16* __restrict__ bs1g, const bf16* __restrict__ bs2g,
    const bf16* __restrict__ vtg, const float* __restrict__ wgb,
    bf16* __restrict__ pacc, float* __restrict__ pl) {
  __shared__ __align__(16) bf16 vbuf[256][72];    // V tile, padded rows (144B)
  __shared__ __align__(16) bf16 kbuf[2][64][40];  // K tile dbuf, padded rows (80B)
  __shared__ __align__(16) bf16 bbuf[2][64][40];  // B2 tile dbuf
  __shared__ __align__(16) bf16 plds[4][16][72];  // per-wave P relayout
  const int blk = blockIdx.x;
  const int rt  = blk >> 2;
  const int os  = blk & 3;
  const int b   = rt >> 6;
  const int row0 = (rt & 63) * 64;
  const int w    = threadIdx.x >> 6;
  const int lane = threadIdx.x & 63;
  const int cl = lane & 15;
  const int kh = lane >> 4;
  const int kb = os * 1024;
  const float wscale = wgb[0] * (1.f / 9.f);
  const v4f vzero = {0.f, 0.f, 0.f, 0.f};
  const size_t qoff = ((size_t)(b * HW + row0 + w * 16 + cl)) * KC + kh * 8;
  const v8bf qf  = *(const v8bf*)(qtg + qoff);
  const v8bf b1f = *(const v8bf*)(bs1g + qoff);
  const bf16* kt = ktg + (size_t)b * HW * KC;
  const bf16* b2 = bs2g + (size_t)b * HW * KC;
  const bf16* vt = vtg + (size_t)b * CH * VSTRIDE;
  // staging lane roles
  const int krow = w * 16 + (lane >> 2), kslot = (lane & 3) * 8;   // K/B2: 16 rows/wave
  const int vch  = w * 64 + (lane >> 3), vslot = (lane & 7) * 8;   // V: 64 ch/wave (per i: +8)

  // prologue: stage K/B2 for step 0
  {
    v8bf kr = *(const v8bf*)(kt + (size_t)(kb + krow) * KC + kslot);
    v8bf br = *(const v8bf*)(b2 + (size_t)(kb + krow) * KC + kslot);
    *(v8bf*)&kbuf[0][krow][kslot] = kr;
    *(v8bf*)&bbuf[0][krow][kslot] = br;
  }
  __syncthreads();

  v4f acc[16];
  #pragma unroll
  for (int f = 0; f < 16; ++f) acc[f] = vzero;
  float psum[4] = {0.f, 0.f, 0.f, 0.f};

  for (int s = 0; s < 16; ++s) {
    const int m0 = kb + s * 64;
    const int pb = s & 1;
    // issue V tile loads (consumed after QK)
    v8bf vr[8];
    #pragma unroll
    for (int i = 0; i < 8; ++i)
      vr[i] = *(const v8bf*)(vt + (size_t)(vch + i * 8) * VSTRIDE + m0 + vslot);
    // issue next-step K/B2 loads
    v8bf kr, br;
    if (s + 1 < 16) {
      kr = *(const v8bf*)(kt + (size_t)(m0 + 64 + krow) * KC + kslot);
      br = *(const v8bf*)(b2 + (size_t)(m0 + 64 + krow) * KC + kslot);
    }
    // QK + bias from LDS
    v4f sim[4], bia[4];
    #pragma unroll
    for (int cb = 0; cb < 4; ++cb) {
      v8bf kf  = *(const v8bf*)&kbuf[pb][cb * 16 + cl][kh * 8];
      v8bf b2f = *(const v8bf*)&bbuf[pb][cb * 16 + cl][kh * 8];
      sim[cb] = __builtin_amdgcn_mfma_f32_16x16x32_bf16(qf,  kf,  vzero, 0, 0, 0);
      bia[cb] = __builtin_amdgcn_mfma_f32_16x16x32_bf16(b1f, b2f, vzero, 0, 0, 0);
    }
    // bounded scores: exp without max subtraction (e^M cancels in p/sum)
    float p[4][4];
    #pragma unroll
    for (int cb = 0; cb < 4; ++cb)
      #pragma unroll
      for (int r = 0; r < 4; ++r) {
        float z = wscale * bia[cb][r];
        float bm = 1.f / (1.f + __expf(-z));
        float pv = __expf(sim[cb][r] * bm);
        p[cb][r] = pv;
        psum[r] += pv;
      }
    // P relayout via per-wave LDS (C-layout row=qrow kh*4+r, col=key cb*16+cl)
    #pragma unroll
    for (int cb = 0; cb < 4; ++cb)
      #pragma unroll
      for (int r = 0; r < 4; ++r)
        plds[w][kh * 4 + r][cb * 16 + cl] = (bf16)p[cb][r];
    asm volatile("s_waitcnt lgkmcnt(0)" ::: "memory");
    __builtin_amdgcn_sched_barrier(0);
    const v8bf pa0 = *(const v8bf*)&plds[w][cl][kh * 8];
    const v8bf pa1 = *(const v8bf*)&plds[w][cl][32 + kh * 8];
    // stage V tile (vmcnt for vr inserted by compiler; K-next stays in flight)
    #pragma unroll
    for (int i = 0; i < 8; ++i)
      *(v8bf*)&vbuf[vch + i * 8][vslot] = vr[i];
    __syncthreads();
    // PV from LDS
    #pragma unroll
    for (int f = 0; f < 16; ++f) {
      v8bf v0 = *(const v8bf*)&vbuf[f * 16 + cl][kh * 8];
      v8bf v1 = *(const v8bf*)&vbuf[f * 16 + cl][32 + kh * 8];
      acc[f] = __builtin_amdgcn_mfma_f32_16x16x32_bf16(pa0, v0, acc[f], 0, 0, 0);
      acc[f] = __builtin_amdgcn_mfma_f32_16x16x32_bf16(pa1, v1, acc[f], 0, 0, 0);
    }
    // stage next K/B2
    if (s + 1 < 16) {
      *(v8bf*)&kbuf[pb ^ 1][krow][kslot] = kr;
      *(v8bf*)&bbuf[pb ^ 1][krow][kslot] = br;
    }
    __syncthreads();   // vbuf consumed + next K ready
  }

  // ---- epilogue: per-wave (waves own disjoint rows; no cross-wave reduce) ----
  // denominator: reduce psum over cl (lane bits 0-3)
  #pragma unroll
  for (int r = 0; r < 4; ++r) {
    float s = psum[r];
    s += __shfl_xor(s, 1);
    s += __shfl_xor(s, 2);
    s += __shfl_xor(s, 4);
    s += __shfl_xor(s, 8);
    if (cl == 0) pl[blk * 64 + w * 16 + kh * 4 + r] = s;
  }
  // acc store via per-wave LDS transpose for coalescing
  bf16* po = pacc + (size_t)blk * 64 * CH;
  for (int c4 = 0; c4 < 4; ++c4) {
    #pragma unroll
    for (int ff = 0; ff < 4; ++ff)
      #pragma unroll
      for (int r = 0; r < 4; ++r)
        plds[w][kh * 4 + r][ff * 16 + cl] = (bf16)acc[c4 * 4 + ff][r];
    asm volatile("s_waitcnt lgkmcnt(0)" ::: "memory");
    __builtin_amdgcn_sched_barrier(0);
    #pragma unroll
    for (int it = 0; it < 2; ++it) {
      int row = lane >> 2, chunk = it * 4 + (lane & 3);
      v8bf d = *(const v8bf*)&plds[w][row][chunk * 8];
      *(v8bf*)&po[(size_t)(w * 16 + row) * CH + c4 * 64 + chunk * 8] = d;
    }
  }
}

// ---------------- K4b: split-K combine (plain sum + divide) ----------------
__global__ __launch_bounds__(256) void k_combine(const bf16* __restrict__ pacc,
    const float* __restrict__ pl, bf16* __restrict__ ctx) {
  const int r = blockIdx.x * 4 + (threadIdx.x >> 6);   // global row 0..8191
  const int lane = threadIdx.x & 63;
  const int rt = r >> 6;
  const int rl = r & 63;
  const int base = rt * 4;
  float den = 0.f;
  #pragma unroll
  for (int s = 0; s < 4; ++s) den += pl[(base + s) * 64 + rl];
  const float inv = 1.f / den;
  #pragma unroll
  for (int c0 = 0; c0 < CH; c0 += 64) {
    int c = c0 + lane;
    float a = 0.f;
    #pragma unroll
    for (int s = 0; s < 4; ++s)
      a += (float)pacc[((size_t)(base + s) * 64 + rl) * CH + c];
    ctx[(size_t)r * CH + c] = (bf16)(a * inv);
  }
}

// ---------------- K5: output 1x1 conv + BN + ReLU + residual ----------------
__global__ __launch_bounds__(256, 2) void k_out(
    const bf16* __restrict__ ctx, const float* __restrict__ Wo,
    const float* __restrict__ bns, const float* __restrict__ bnb,
    const float* __restrict__ bnm, const float* __restrict__ bnv,
    const float* __restrict__ gamma, const float* __restrict__ x,
    float* __restrict__ out) {
  __shared__ __align__(16) float cs[CH * 36];
  const int blk  = blockIdx.x;
  const int half = blk & 1;
  const int nn   = (blk >> 1) & 127;
  const int b    = blk >> 8;
  const int n0   = nn * 32;
  const int t    = threadIdx.x;
  for (int i = t; i < 32 * 256; i += 256) {
    int j = i >> 8, c = i & 255;
    cs[c * 36 + j] = (float)ctx[((size_t)b * HW + n0 + j) * CH + c];
  }
  __syncthreads();
  const int og = t >> 3, jg = t & 7;
  float acc[4][4];
  #pragma unroll
  for (int oo = 0; oo < 4; ++oo)
    #pragma unroll
    for (int jj = 0; jj < 4; ++jj) acc[oo][jj] = 0.f;
  const int o0 = half * 128 + og * 4;
  for (int c0 = 0; c0 < CH; c0 += 4) {
    v4f xv[4];
    #pragma unroll
    for (int cc = 0; cc < 4; ++cc)
      xv[cc] = *(const v4f*)&cs[(c0 + cc) * 36 + jg * 4];
    #pragma unroll
    for (int oo = 0; oo < 4; ++oo) {
      v4f wv = *(const v4f*)&Wo[(o0 + oo) * CH + c0];
      #pragma unroll
      for (int cc = 0; cc < 4; ++cc)
        #pragma unroll
        for (int jj = 0; jj < 4; ++jj)
          acc[oo][jj] += wv[cc] * xv[cc][jj];
    }
  }
  const float g = gamma[0];
  #pragma unroll
  for (int oo = 0; oo < 4; ++oo) {
    int o = o0 + oo;
    float isc = bns[o] / sqrtf(bnv[o] + BNEPS);
    float mu = bnm[o], bb = bnb[o];
    #pragma unroll
    for (int jj = 0; jj < 4; ++jj) {
      int n = n0 + jg * 4 + jj;
      float v = (acc[oo][jj] - mu) * isc + bb;
      v = fmaxf(v, 0.f);
      size_t oi = ((size_t)b * CH + o) * HW + n;
      out[oi] = g * v + x[oi];
    }
  }
}

// ---------------- launch ----------------
extern "C" void kernel_launch(void* const* d_in, const int* in_sizes, int n_in,
                              void* d_out, int out_size, void* d_ws, size_t ws_size,
                              hipStream_t stream) {
  const float* x    = (const float*)d_in[0];
  const float* Wq   = (const float*)d_in[1];
  const float* Wk   = (const float*)d_in[2];
  const float* Wv   = (const float*)d_in[3];
  const float* Wb1  = (const float*)d_in[4];
  const float* Wb2  = (const float*)d_in[5];
  const float* wgb  = (const float*)d_in[6];
  const float* gw1  = (const float*)d_in[7];
  const float* gb1  = (const float*)d_in[8];
  const float* gw2  = (const float*)d_in[9];
  const float* gb2  = (const float*)d_in[10];
  const float* Wo   = (const float*)d_in[11];
  const float* bns  = (const float*)d_in[12];
  const float* bnb  = (const float*)d_in[13];
  const float* bnm  = (const float*)d_in[14];
  const float* bnv  = (const float*)d_in[15];
  const float* gam  = (const float*)d_in[16];

  char* ws = (char*)d_ws;
  float* mean = (float*)(ws + OFF_MEAN);
  float* wkb  = (float*)(ws + OFF_WKB);
  bf16* qt    = (bf16*)(ws + OFF_QT);
  bf16* kt    = (bf16*)(ws + OFF_KT);
  bf16* bs1   = (bf16*)(ws + OFF_BS1);
  bf16* bs2   = (bf16*)(ws + OFF_BS2);
  bf16* vt    = (bf16*)(ws + OFF_VT);
  float* b1r  = (float*)(ws + OFF_B1R);
  float* b2r  = (float*)(ws + OFF_B2R);
  bf16* ctx   = (bf16*)(ws + OFF_CTX);
  bf16* pacc  = (bf16*)(ws + OFF_PACC);
  float* plv  = (float*)(ws + OFF_PL);
  float* out  = (float*)d_out;

  hipLaunchKernelGGL(k_mean,    dim3(NB * CH),        dim3(256), 0, stream, x, mean);
  hipLaunchKernelGGL(k_gate,    dim3(NB),             dim3(256), 0, stream, mean, gw1, gb1, gw2, gb2, Wk, wkb);
  hipLaunchKernelGGL(k_proj,    dim3(NB * 128 * 2),   dim3(256), 0, stream, x, Wq, wkb, Wb1, Wb2, Wv, qt, kt, b1r, b2r, vt);
  hipLaunchKernelGGL(k_pool,    dim3(NB * HW * KC / 256), dim3(256), 0, stream, b1r, b2r, bs1, bs2);
  hipLaunchKernelGGL(k_attn,    dim3(512),            dim3(256), 0, stream, qt, kt, bs1, bs2, vt, wgb, pacc, plv);
  hipLaunchKernelGGL(k_combine, dim3(NB * HW / 4),    dim3(256), 0, stream, pacc, plv, ctx);
  hipLaunchKernelGGL(k_out,     dim3(NB * 128 * 2),   dim3(256), 0, stream, ctx, Wo, bns, bnb, bnm, bnv, gam, x, out);
}